// Round 1
// baseline (383.492 us; speedup 1.0000x reference)
//
#include <hip/hip_runtime.h>
#include <math.h>

#define NODES   50000
#define HEADS   4
#define HID     64
#define FDIM    256   // HEADS*HID
#define IN_CH   16
#define NEG_SLOPE 0.2f

typedef unsigned short ushort_t;
typedef unsigned int uint_t;
typedef __attribute__((ext_vector_type(8))) short bf16x8;
typedef __attribute__((ext_vector_type(4))) float f32x4;

__device__ inline ushort_t f2bf(float f) {           // RNE fp32 -> bf16
    uint_t u = __float_as_uint(f);
    u += 0x7fffu + ((u >> 16) & 1u);
    return (ushort_t)(u >> 16);
}
__device__ inline uint_t f2h(float f) {              // fp32 -> fp16 bits (RTE)
    _Float16 h = (_Float16)f;
    return (uint_t)*(ushort_t*)&h;
}
__device__ inline float h2f(uint_t u) {              // fp16 bits -> fp32
    ushort_t us = (ushort_t)u;
    _Float16 h = *(_Float16*)&us;
    return (float)h;
}

// 8 channels: acc[j] += pw * fp16(hv half j) via v_fma_mix_f32 (1 instr/channel,
// no unpack shifts). src1 = f16 (op_sel_hi[1]=1), op_sel[1] picks lo/hi half.
__device__ inline void fmamix8(float* a, uint4 hv, float pw) {
    asm("v_fma_mix_f32 %0, %8, %9, %0 op_sel:[0,0,0] op_sel_hi:[0,1,0]\n\t"
        "v_fma_mix_f32 %1, %8, %9, %1 op_sel:[0,1,0] op_sel_hi:[0,1,0]\n\t"
        "v_fma_mix_f32 %2, %8, %10, %2 op_sel:[0,0,0] op_sel_hi:[0,1,0]\n\t"
        "v_fma_mix_f32 %3, %8, %10, %3 op_sel:[0,1,0] op_sel_hi:[0,1,0]\n\t"
        "v_fma_mix_f32 %4, %8, %11, %4 op_sel:[0,0,0] op_sel_hi:[0,1,0]\n\t"
        "v_fma_mix_f32 %5, %8, %11, %5 op_sel:[0,1,0] op_sel_hi:[0,1,0]\n\t"
        "v_fma_mix_f32 %6, %8, %12, %6 op_sel:[0,0,0] op_sel_hi:[0,1,0]\n\t"
        "v_fma_mix_f32 %7, %8, %12, %7 op_sel:[0,1,0] op_sel_hi:[0,1,0]"
        : "+v"(a[0]), "+v"(a[1]), "+v"(a[2]), "+v"(a[3]),
          "+v"(a[4]), "+v"(a[5]), "+v"(a[6]), "+v"(a[7])
        : "v"(pw), "v"(hv.x), "v"(hv.y), "v"(hv.z), "v"(hv.w));
}

// ---------------- merged: layer-1 GEMM + alpha1 (8 nodes/block) | W2T | hist ----------------
// h is stored as fp16 now (consumed only by k_agg's fma_mix path).

__global__ __launch_bounds__(256) void k_prep(const float* __restrict__ x,
                                              const float* __restrict__ W1,
                                              const float* __restrict__ as1,
                                              const float* __restrict__ ad1,
                                              const float* __restrict__ W2,
                                              const int* __restrict__ ei, int E,
                                              ushort_t* __restrict__ h,
                                              float* __restrict__ asrc,
                                              float* __restrict__ adst,
                                              ushort_t* __restrict__ W2T,
                                              int* __restrict__ deg, int Nn, int NB) {
    int bid = blockIdx.x, t = threadIdx.x;
    if (bid >= NB + 256) {                 // histogram tail
        int e = (bid - NB - 256) * 256 + t;
        int Etot = E + Nn;
        if (e >= Etot) return;
        int d = (e < E) ? ei[E + e] : (e - E);
        if (d >= 0 && d < Nn) atomicAdd(&deg[d], 1);
        return;
    }
    if (bid >= NB) {                       // W2T: 256 blocks, 65536 elements (bf16, MFMA operand)
        int idx = (bid - NB) * 256 + t;
        int n = idx >> 8, k = idx & 255;
        W2T[idx] = f2bf(W2[k * FDIM + n]);
        return;
    }
    float w1c[16];
#pragma unroll
    for (int k = 0; k < 16; ++k) w1c[k] = W1[k * FDIM + t];
    float av = as1[t], dv = ad1[t];       // as1/ad1 are [H][64] flat == [t]
    int hh = t >> 6;
#pragma unroll
    for (int j = 0; j < 8; ++j) {
        int n = bid * 8 + j;
        if (n >= Nn) break;
        const float4* xp = (const float4*)(x + n * IN_CH);
        float4 x0 = xp[0], x1 = xp[1], x2 = xp[2], x3 = xp[3];
        float s = x0.x * w1c[0]  + x0.y * w1c[1]  + x0.z * w1c[2]  + x0.w * w1c[3]
                + x1.x * w1c[4]  + x1.y * w1c[5]  + x1.z * w1c[6]  + x1.w * w1c[7]
                + x2.x * w1c[8]  + x2.y * w1c[9]  + x2.z * w1c[10] + x2.w * w1c[11]
                + x3.x * w1c[12] + x3.y * w1c[13] + x3.z * w1c[14] + x3.w * w1c[15];
        uint_t pv = f2h(s);
        uint_t ov = __shfl_down(pv, 1);
        if (!(t & 1)) *(uint_t*)(h + (long)n * FDIM + t) = pv | (ov << 16);
        float p1 = s * av, p2 = s * dv;
#pragma unroll
        for (int off = 1; off < 64; off <<= 1) {
            p1 += __shfl_xor(p1, off);
            p2 += __shfl_xor(p2, off);
        }
        if ((t & 63) == 0) {
            asrc[n * 4 + hh] = p1;
            adst[n * 4 + hh] = p2;
        }
    }
}

// ---------------- parallel exclusive scan ----------------

__global__ __launch_bounds__(256) void k_scanA(const int* __restrict__ deg,
                                               int* __restrict__ bsum, int N) {
    __shared__ int sh[256];
    int t = threadIdx.x;
    int i0 = blockIdx.x * 4096 + t * 16;
    int s = 0;
#pragma unroll
    for (int j = 0; j < 16; ++j) s += (i0 + j < N) ? deg[i0 + j] : 0;
    sh[t] = s;
    __syncthreads();
    for (int off = 128; off; off >>= 1) {
        if (t < off) sh[t] += sh[t + off];
        __syncthreads();
    }
    if (t == 0) bsum[blockIdx.x] = sh[0];
}

__global__ void k_scanB(int* __restrict__ bsum, int* __restrict__ rowst, int nb, int N) {
    int t = threadIdx.x;   // single wave of 64
    int orig = (t < nb) ? bsum[t] : 0;
    int v = orig;
#pragma unroll
    for (int off = 1; off < 64; off <<= 1) {
        int u = __shfl_up(v, off);
        if (t >= off) v += u;
    }
    if (t < nb) bsum[t] = v - orig;       // exclusive
    if (t == 63) rowst[N] = v;            // grand total
}

__global__ __launch_bounds__(256) void k_scanC(const int* __restrict__ deg,
                                               const int* __restrict__ bsum,
                                               int* __restrict__ rowst,
                                               int* __restrict__ cursor, int N) {
    __shared__ int sh[256];
    int t = threadIdx.x, b = blockIdx.x;
    int i0 = b * 4096 + t * 16;
    int v[16], s = 0;
#pragma unroll
    for (int j = 0; j < 16; ++j) { v[j] = (i0 + j < N) ? deg[i0 + j] : 0; s += v[j]; }
    sh[t] = s;
    __syncthreads();
    for (int off = 1; off < 256; off <<= 1) {
        int u = (t >= off) ? sh[t - off] : 0;
        __syncthreads();
        sh[t] += u;
        __syncthreads();
    }
    int excl = sh[t] - s + bsum[b];
#pragma unroll
    for (int j = 0; j < 16; ++j) {
        if (i0 + j < N) { rowst[i0 + j] = excl; cursor[i0 + j] = excl; }
        excl += v[j];
    }
}

__global__ void k_scatter(const int* __restrict__ ei, int E, int N,
                          int* __restrict__ cursor, int2* __restrict__ csr2) {
    int e = blockIdx.x * blockDim.x + threadIdx.x;
    int Etot = E + N;
    if (e >= Etot) return;
    int s, d;
    if (e < E) { s = ei[e]; d = ei[E + e]; } else { s = d = e - E; }
    if (d < 0 || d >= N) return;
    int pos = atomicAdd(&cursor[d], 1);
    csr2[pos] = make_int2(s, d);
}

// ---------------- layer-2 GEMM (MFMA bf16) + fused alpha2 dots ----------------
// col tile (64) == one head, so each block owns complete (row, head) dot products.
// C is written as fp16 (consumed only by k_agg mode 0).

__global__ __launch_bounds__(256) void k_gemm2(const ushort_t* __restrict__ A,
                                               const ushort_t* __restrict__ BT,
                                               const float* __restrict__ as2,
                                               const float* __restrict__ ad2,
                                               ushort_t* __restrict__ C,
                                               float* __restrict__ asrc,
                                               float* __restrict__ adst, int M) {
    __shared__ short As[64 * 40];
    __shared__ short Bs[64 * 40];
    __shared__ float2 red[64][2];
    int tid = threadIdx.x;
    int row0 = blockIdx.y * 64, col0 = blockIdx.x * 64;
    int wid = tid >> 6, lane = tid & 63;
    int wm = wid >> 1, wn = wid & 1;
    int quad = lane >> 4, lm = lane & 15;
    int lr = tid >> 2, lk = (tid & 3) * 8;
    f32x4 acc[2][2] = {};
    for (int k0 = 0; k0 < FDIM; k0 += 32) {
        uint4 av = {0u, 0u, 0u, 0u};
        int ar = row0 + lr;
        if (ar < M) av = *(const uint4*)(A + (long)ar * FDIM + k0 + lk);
        *(uint4*)(&As[lr * 40 + lk]) = av;
        uint4 bv = *(const uint4*)(BT + (long)(col0 + lr) * FDIM + k0 + lk);
        *(uint4*)(&Bs[lr * 40 + lk]) = bv;
        __syncthreads();
        bf16x8 a0 = *(const bf16x8*)(&As[(wm * 32 + lm) * 40 + quad * 8]);
        bf16x8 a1 = *(const bf16x8*)(&As[(wm * 32 + 16 + lm) * 40 + quad * 8]);
        bf16x8 b0 = *(const bf16x8*)(&Bs[(wn * 32 + lm) * 40 + quad * 8]);
        bf16x8 b1 = *(const bf16x8*)(&Bs[(wn * 32 + 16 + lm) * 40 + quad * 8]);
        acc[0][0] = __builtin_amdgcn_mfma_f32_16x16x32_bf16(a0, b0, acc[0][0], 0, 0, 0);
        acc[0][1] = __builtin_amdgcn_mfma_f32_16x16x32_bf16(a0, b1, acc[0][1], 0, 0, 0);
        acc[1][0] = __builtin_amdgcn_mfma_f32_16x16x32_bf16(a1, b0, acc[1][0], 0, 0, 0);
        acc[1][1] = __builtin_amdgcn_mfma_f32_16x16x32_bf16(a1, b1, acc[1][1], 0, 0, 0);
        __syncthreads();
    }
    // C store (fp16)
#pragma unroll
    for (int mi = 0; mi < 2; ++mi)
#pragma unroll
        for (int ni = 0; ni < 2; ++ni)
#pragma unroll
            for (int r = 0; r < 4; ++r) {
                int row = row0 + wm * 32 + mi * 16 + quad * 4 + r;
                int col = col0 + wn * 32 + ni * 16 + lm;
                if (row < M) C[(long)row * FDIM + col] = (ushort_t)f2h(acc[mi][ni][r]);
            }
    // fused alpha2: per-row dots vs as2/ad2 (this block's head = blockIdx.x)
    float asv0 = as2[col0 + wn * 32 + lm], asv1 = as2[col0 + wn * 32 + 16 + lm];
    float adv0 = ad2[col0 + wn * 32 + lm], adv1 = ad2[col0 + wn * 32 + 16 + lm];
#pragma unroll
    for (int mi = 0; mi < 2; ++mi)
#pragma unroll
        for (int r = 0; r < 4; ++r) {
            float ps = acc[mi][0][r] * asv0 + acc[mi][1][r] * asv1;
            float pd = acc[mi][0][r] * adv0 + acc[mi][1][r] * adv1;
#pragma unroll
            for (int off = 1; off < 16; off <<= 1) {
                ps += __shfl_xor(ps, off);
                pd += __shfl_xor(pd, off);
            }
            if (lm == 0) red[wm * 32 + mi * 16 + quad * 4 + r][wn] = make_float2(ps, pd);
        }
    __syncthreads();
    if (tid < 64) {
        int row = row0 + tid;
        if (row < M) {
            float2 e0 = red[tid][0], e1 = red[tid][1];
            asrc[row * 4 + blockIdx.x] = e0.x + e1.x;
            adst[row * 4 + blockIdx.x] = e0.y + e1.y;
        }
    }
}

// ---------------- edge-parallel pw precompute: u32 = (src<<16) | fp16(pw) ----------------

__global__ void k_pw(const int2* __restrict__ csr2, const float* __restrict__ asrc,
                     const float* __restrict__ adst, uint_t* __restrict__ pwb, int Etot) {
    int e = blockIdx.x * blockDim.x + threadIdx.x;
    if (e >= Etot) return;
    int2 sd = csr2[e];
    float4 av = *(const float4*)(asrc + sd.x * 4);
    float4 dv = *(const float4*)(adst + sd.y * 4);
    float t[4] = {av.x + dv.x, av.y + dv.y, av.z + dv.z, av.w + dv.w};
    uint_t sh = (uint_t)sd.x << 16;
#pragma unroll
    for (int h = 0; h < 4; ++h) {
        float tt = (t[h] > 0.f) ? t[h] : NEG_SLOPE * t[h];
        pwb[h * Etot + e] = sh | f2h(__expf(tt));
    }
}

// ---------------- segment-softmax aggregate (pwb, 4x in flight, fused epilogues) ----------------
// fp16 h + v_fma_mix accumulate; 32-bit byte offsets against uniform bases so the
// compiler can emit global_load saddr form (no per-lane 64-bit adds).

__global__ __launch_bounds__(256) void k_agg(const ushort_t* __restrict__ h,
                                             const uint_t* __restrict__ pwb,
                                             const int* __restrict__ row_start,
                                             const float* __restrict__ b1,
                                             const float* __restrict__ b2,
                                             const float* __restrict__ Wc,
                                             const float* __restrict__ bc,
                                             ushort_t* __restrict__ hout,
                                             float* __restrict__ fout,
                                             int mode, int Etot, int N) {
    __shared__ float zsh[2 * FDIM];    // 2 nodes x 256 ch (head-major)
    __shared__ float wsh[584];         // Wc(512) | bc(8) | b2(64)
    int tid  = threadIdx.x;
    int hh   = tid >> 6;
    int lane = tid & 63;
    int half = lane >> 5;
    int l32  = lane & 31;
    int g    = l32 >> 3;       // edge subgroup 0..3
    int cg   = l32 & 7;        // channel oct 0..7
    int d    = blockIdx.x * 2 + half;
    bool valid = d < N;

    if (!mode) {
        for (int i = tid; i < 584; i += 256)
            wsh[i] = (i < 512) ? Wc[i] : ((i < 520) ? bc[i - 512] : b2[i - 520]);
    }

    int s0 = 0, s1 = 0;
    if (valid) { s0 = row_start[d]; s1 = row_start[d + 1]; }
    int cnt  = s1 - s0;
    int maxc = max(cnt, __shfl_xor(cnt, 32));

    const char* hb  = (const char*)h;
    const char* pwc = (const char*)pwb;
    uint_t loff  = ((uint_t)hh * HID + (uint_t)cg * 8) * 2;               // lane byte off in h row
    uint_t pbyte = ((uint_t)hh * (uint_t)Etot + (uint_t)(s0 + g)) << 2;   // pwb byte base

    float acc[8] = {0.f, 0.f, 0.f, 0.f, 0.f, 0.f, 0.f, 0.f};
    float den = 0.f;

    for (int off = 0; off < maxc; off += 16) {
        int i0 = s0 + off + g;
        uint_t pb = pbyte + ((uint_t)off << 2);
        uint_t u0 = (i0      < s1) ? *(const uint_t*)(pwc + pb)      : 0u;
        uint_t u1 = (i0 + 4  < s1) ? *(const uint_t*)(pwc + pb + 16) : 0u;
        uint_t u2 = (i0 + 8  < s1) ? *(const uint_t*)(pwc + pb + 32) : 0u;
        uint_t u3 = (i0 + 12 < s1) ? *(const uint_t*)(pwc + pb + 48) : 0u;
        uint4 hv0 = *(const uint4*)(hb + (((u0 >> 16) << 9) + loff));
        uint4 hv1 = *(const uint4*)(hb + (((u1 >> 16) << 9) + loff));
        uint4 hv2 = *(const uint4*)(hb + (((u2 >> 16) << 9) + loff));
        uint4 hv3 = *(const uint4*)(hb + (((u3 >> 16) << 9) + loff));
        float pw0 = h2f(u0), pw1 = h2f(u1);
        float pw2 = h2f(u2), pw3 = h2f(u3);
        den += (pw0 + pw1) + (pw2 + pw3);
        fmamix8(acc, hv0, pw0);
        fmamix8(acc, hv1, pw1);
        fmamix8(acc, hv2, pw2);
        fmamix8(acc, hv3, pw3);
    }
    // reduce across the 4 edge-subgroups within each 32-lane half
#pragma unroll
    for (int off = 8; off <= 16; off <<= 1) {
#pragma unroll
        for (int j = 0; j < 8; ++j) acc[j] += __shfl_xor(acc[j], off);
        den += __shfl_xor(den, off);
    }

    if (mode) {
        if (g == 0 && valid) {
            float inv = 1.f / den;
            const float* bp = b1 + hh * HID + cg * 8;
            float v[8];
#pragma unroll
            for (int j = 0; j < 8; ++j) {
                float t = acc[j] * inv + bp[j];
                v[j] = (t > 0.f) ? t : __expf(t) - 1.f;
            }
            uint4 u;
            u.x = (uint_t)f2bf(v[0]) | ((uint_t)f2bf(v[1]) << 16);
            u.y = (uint_t)f2bf(v[2]) | ((uint_t)f2bf(v[3]) << 16);
            u.z = (uint_t)f2bf(v[4]) | ((uint_t)f2bf(v[5]) << 16);
            u.w = (uint_t)f2bf(v[6]) | ((uint_t)f2bf(v[7]) << 16);
            *(uint4*)(hout + (long)d * FDIM + hh * HID + cg * 8) = u;
        }
    } else {
        if (g == 0 && valid) {
            float inv = 1.f / den;
            int zb = half * FDIM + hh * HID + cg * 8;
#pragma unroll
            for (int j = 0; j < 8; ++j) zsh[zb + j] = acc[j] * inv;
        }
        __syncthreads();
        if (tid < 128) {                 // head-mean + b2 + ELU
            int node = tid >> 6, c = tid & 63;
            int dd = blockIdx.x * 2 + node;
            if (dd < N) {
                const float* zp = zsh + node * FDIM;
                float zv = 0.25f * (zp[c] + zp[64 + c] + zp[128 + c] + zp[192 + c])
                         + wsh[520 + c];
                zv = (zv > 0.f) ? zv : __expf(zv) - 1.f;
                zsh[node * FDIM + c] = zv;
            }
        }
        __syncthreads();
        if (tid < 16) {                  // GEMV [64x8] + bc
            int node = tid >> 3, o = tid & 7;
            int dd = blockIdx.x * 2 + node;
            if (dd < N) {
                float acc2 = wsh[512 + o];
                const float* zp = zsh + node * FDIM;
#pragma unroll 8
                for (int c = 0; c < 64; ++c) acc2 += zp[c] * wsh[c * 8 + o];
                fout[(long)dd * 8 + o] = acc2;
            }
        }
    }
}

// ---------------- launch ----------------

extern "C" void kernel_launch(void* const* d_in, const int* in_sizes, int n_in,
                              void* d_out, int out_size, void* d_ws, size_t ws_size,
                              hipStream_t stream) {
    const float* x   = (const float*)d_in[0];
    const int*   ei  = (const int*)d_in[1];
    const float* W1  = (const float*)d_in[2];
    const float* as1 = (const float*)d_in[3];
    const float* ad1 = (const float*)d_in[4];
    const float* b1  = (const float*)d_in[5];
    const float* W2  = (const float*)d_in[6];
    const float* as2 = (const float*)d_in[7];
    const float* ad2 = (const float*)d_in[8];
    const float* b2  = (const float*)d_in[9];
    const float* Wc  = (const float*)d_in[10];
    const float* bc  = (const float*)d_in[11];
    float* out = (float*)d_out;

    const int N = NODES;
    const int E = in_sizes[1] / 2;
    const int Etot = E + N;

    char* ws = (char*)d_ws;
    size_t off = 0;
    auto alloc = [&](size_t bytes) {
        void* p = ws + off;
        off = (off + bytes + 255) & ~(size_t)255;
        return p;
    };
    ushort_t* hbf    = (ushort_t*)alloc((size_t)N * FDIM * 2);   // h (fp16), both layers
    ushort_t* hact   = (ushort_t*)alloc((size_t)N * FDIM * 2);   // act1 (bf16, MFMA operand)
    float*    asrc   = (float*)alloc((size_t)N * HEADS * 4);
    float*    adst   = (float*)alloc((size_t)N * HEADS * 4);
    ushort_t* W2T    = (ushort_t*)alloc((size_t)FDIM * FDIM * 2);
    int*      deg    = (int*)alloc((size_t)N * 4);
    int*      rowst  = (int*)alloc((size_t)(N + 1) * 4);
    int*      cursor = (int*)alloc((size_t)N * 4);
    int*      bsum   = (int*)alloc(64 * 4);
    int2*     csr2   = (int2*)alloc((size_t)Etot * 8);
    uint_t*   pwb    = (uint_t*)alloc((size_t)Etot * HEADS * 4);

    const int tpb = 256;
    int egrid = (Etot + tpb - 1) / tpb;
    int nb = (N + 4095) / 4096;
    int NB = (N + 7) / 8;

    hipMemsetAsync(deg, 0, (size_t)N * 4, stream);

    // Merged: layer-1 gemm+alpha | W2T | histogram
    k_prep<<<NB + 256 + egrid, tpb, 0, stream>>>(x, W1, as1, ad1, W2, ei, E,
                                                 hbf, asrc, adst, W2T, deg, N, NB);
    k_scanA<<<nb, 256, 0, stream>>>(deg, bsum, N);
    k_scanB<<<1, 64, 0, stream>>>(bsum, rowst, nb, N);
    k_scanC<<<nb, 256, 0, stream>>>(deg, bsum, rowst, cursor, N);
    k_scatter<<<egrid, tpb, 0, stream>>>(ei, E, N, cursor, csr2);

    // Layer 1 aggregate (+b1, ELU)
    k_pw<<<egrid, tpb, 0, stream>>>(csr2, asrc, adst, pwb, Etot);
    k_agg<<<(N + 1) / 2, 256, 0, stream>>>(hbf, pwb, rowst, b1, nullptr, nullptr, nullptr,
                                           hact, nullptr, 1, Etot, N);

    // Layer 2 (gemm + fused alpha2)
    dim3 g2(FDIM / 64, (N + 63) / 64);
    k_gemm2<<<g2, 256, 0, stream>>>(hact, W2T, as2, ad2, hbf, asrc, adst, N);
    k_pw<<<egrid, tpb, 0, stream>>>(csr2, asrc, adst, pwb, Etot);
    k_agg<<<(N + 1) / 2, 256, 0, stream>>>(hbf, pwb, rowst, nullptr, b2, Wc, bc,
                                           nullptr, out, 0, Etot, N);
}

// Round 3
// 374.065 us; speedup vs baseline: 1.0252x; 1.0252x over previous
//
#include <hip/hip_runtime.h>
#include <math.h>

#define NODES   50000
#define HEADS   4
#define HID     64
#define FDIM    256   // HEADS*HID
#define IN_CH   16
#define NEG_SLOPE 0.2f

typedef unsigned short ushort_t;
typedef unsigned int uint_t;
typedef __attribute__((ext_vector_type(8))) short bf16x8;
typedef __attribute__((ext_vector_type(4))) float f32x4;
typedef __attribute__((ext_vector_type(4))) uint_t u32x4;

__device__ inline ushort_t f2bf(float f) {           // RNE fp32 -> bf16
    uint_t u = __float_as_uint(f);
    u += 0x7fffu + ((u >> 16) & 1u);
    return (ushort_t)(u >> 16);
}
__device__ inline uint_t f2h(float f) {              // fp32 -> fp16 bits (RTE)
    _Float16 h = (_Float16)f;
    return (uint_t)*(ushort_t*)&h;
}
__device__ inline float h2f(uint_t u) {              // fp16 bits -> fp32
    ushort_t us = (ushort_t)u;
    _Float16 h = *(_Float16*)&us;
    return (float)h;
}

// 8 channels: acc[j] += pw * fp16(hv half j) via v_fma_mix_f32 (1 instr/channel).
__device__ inline void fmamix8(float* a, uint4 hv, float pw) {
    asm("v_fma_mix_f32 %0, %8, %9, %0 op_sel:[0,0,0] op_sel_hi:[0,1,0]\n\t"
        "v_fma_mix_f32 %1, %8, %9, %1 op_sel:[0,1,0] op_sel_hi:[0,1,0]\n\t"
        "v_fma_mix_f32 %2, %8, %10, %2 op_sel:[0,0,0] op_sel_hi:[0,1,0]\n\t"
        "v_fma_mix_f32 %3, %8, %10, %3 op_sel:[0,1,0] op_sel_hi:[0,1,0]\n\t"
        "v_fma_mix_f32 %4, %8, %11, %4 op_sel:[0,0,0] op_sel_hi:[0,1,0]\n\t"
        "v_fma_mix_f32 %5, %8, %11, %5 op_sel:[0,1,0] op_sel_hi:[0,1,0]\n\t"
        "v_fma_mix_f32 %6, %8, %12, %6 op_sel:[0,0,0] op_sel_hi:[0,1,0]\n\t"
        "v_fma_mix_f32 %7, %8, %12, %7 op_sel:[0,1,0] op_sel_hi:[0,1,0]"
        : "+v"(a[0]), "+v"(a[1]), "+v"(a[2]), "+v"(a[3]),
          "+v"(a[4]), "+v"(a[5]), "+v"(a[6]), "+v"(a[7])
        : "v"(pw), "v"(hv.x), "v"(hv.y), "v"(hv.z), "v"(hv.w));
}

// ---------------- merged: layer-1 GEMM + alpha1 (8 nodes/block) | W2T | hist ----------------
// h is stored HEAD-MAJOR fp16: h[head][node][64]  (gather tables are per-head sliced
// so each XCD's L2 only sees one 6.4 MB head slice in k_agg).

__global__ __launch_bounds__(256) void k_prep(const float* __restrict__ x,
                                              const float* __restrict__ W1,
                                              const float* __restrict__ as1,
                                              const float* __restrict__ ad1,
                                              const float* __restrict__ W2,
                                              const int* __restrict__ ei, int E,
                                              ushort_t* __restrict__ h,
                                              float* __restrict__ asrc,
                                              float* __restrict__ adst,
                                              ushort_t* __restrict__ W2T,
                                              int* __restrict__ deg, int Nn, int NB) {
    int bid = blockIdx.x, t = threadIdx.x;
    if (bid >= NB + 256) {                 // histogram tail
        int e = (bid - NB - 256) * 256 + t;
        int Etot = E + Nn;
        if (e >= Etot) return;
        int d = (e < E) ? ei[E + e] : (e - E);
        if (d >= 0 && d < Nn) atomicAdd(&deg[d], 1);
        return;
    }
    if (bid >= NB) {                       // W2T: 256 blocks, 65536 elements (bf16, MFMA operand)
        int idx = (bid - NB) * 256 + t;
        int n = idx >> 8, k = idx & 255;
        W2T[idx] = f2bf(W2[k * FDIM + n]);
        return;
    }
    float w1c[16];
#pragma unroll
    for (int k = 0; k < 16; ++k) w1c[k] = W1[k * FDIM + t];
    float av = as1[t], dv = ad1[t];       // as1/ad1 are [H][64] flat == [t]
    int hh = t >> 6;
#pragma unroll
    for (int j = 0; j < 8; ++j) {
        int n = bid * 8 + j;
        if (n >= Nn) break;
        const float4* xp = (const float4*)(x + n * IN_CH);
        float4 x0 = xp[0], x1 = xp[1], x2 = xp[2], x3 = xp[3];
        float s = x0.x * w1c[0]  + x0.y * w1c[1]  + x0.z * w1c[2]  + x0.w * w1c[3]
                + x1.x * w1c[4]  + x1.y * w1c[5]  + x1.z * w1c[6]  + x1.w * w1c[7]
                + x2.x * w1c[8]  + x2.y * w1c[9]  + x2.z * w1c[10] + x2.w * w1c[11]
                + x3.x * w1c[12] + x3.y * w1c[13] + x3.z * w1c[14] + x3.w * w1c[15];
        uint_t pv = f2h(s);
        uint_t ov = __shfl_down(pv, 1);
        if (!(t & 1))
            *(uint_t*)(h + (((long)hh * Nn + n) << 6) + (t & 63)) = pv | (ov << 16);
        float p1 = s * av, p2 = s * dv;
#pragma unroll
        for (int off = 1; off < 64; off <<= 1) {
            p1 += __shfl_xor(p1, off);
            p2 += __shfl_xor(p2, off);
        }
        if ((t & 63) == 0) {
            asrc[n * 4 + hh] = p1;
            adst[n * 4 + hh] = p2;
        }
    }
}

// ---------------- parallel exclusive scan ----------------

__global__ __launch_bounds__(256) void k_scanA(const int* __restrict__ deg,
                                               int* __restrict__ bsum, int N) {
    __shared__ int sh[256];
    int t = threadIdx.x;
    int i0 = blockIdx.x * 4096 + t * 16;
    int s = 0;
#pragma unroll
    for (int j = 0; j < 16; ++j) s += (i0 + j < N) ? deg[i0 + j] : 0;
    sh[t] = s;
    __syncthreads();
    for (int off = 128; off; off >>= 1) {
        if (t < off) sh[t] += sh[t + off];
        __syncthreads();
    }
    if (t == 0) bsum[blockIdx.x] = sh[0];
}

__global__ void k_scanB(int* __restrict__ bsum, int* __restrict__ rowst, int nb, int N) {
    int t = threadIdx.x;   // single wave of 64
    int orig = (t < nb) ? bsum[t] : 0;
    int v = orig;
#pragma unroll
    for (int off = 1; off < 64; off <<= 1) {
        int u = __shfl_up(v, off);
        if (t >= off) v += u;
    }
    if (t < nb) bsum[t] = v - orig;       // exclusive
    if (t == 63) rowst[N] = v;            // grand total
}

__global__ __launch_bounds__(256) void k_scanC(const int* __restrict__ deg,
                                               const int* __restrict__ bsum,
                                               int* __restrict__ rowst,
                                               int* __restrict__ cursor, int N) {
    __shared__ int sh[256];
    int t = threadIdx.x, b = blockIdx.x;
    int i0 = b * 4096 + t * 16;
    int v[16], s = 0;
#pragma unroll
    for (int j = 0; j < 16; ++j) { v[j] = (i0 + j < N) ? deg[i0 + j] : 0; s += v[j]; }
    sh[t] = s;
    __syncthreads();
    for (int off = 1; off < 256; off <<= 1) {
        int u = (t >= off) ? sh[t - off] : 0;
        __syncthreads();
        sh[t] += u;
        __syncthreads();
    }
    int excl = sh[t] - s + bsum[b];
#pragma unroll
    for (int j = 0; j < 16; ++j) {
        if (i0 + j < N) { rowst[i0 + j] = excl; cursor[i0 + j] = excl; }
        excl += v[j];
    }
}

__global__ void k_scatter(const int* __restrict__ ei, int E, int N,
                          int* __restrict__ cursor, int2* __restrict__ csr2) {
    int e = blockIdx.x * blockDim.x + threadIdx.x;
    int Etot = E + N;
    if (e >= Etot) return;
    int s, d;
    if (e < E) { s = ei[e]; d = ei[E + e]; } else { s = d = e - E; }
    if (d < 0 || d >= N) return;
    int pos = atomicAdd(&cursor[d], 1);
    csr2[pos] = make_int2(s, d);
}

// ---------------- layer-2 GEMM (MFMA bf16) + fused alpha2 dots ----------------
// col tile (64) == one head == blockIdx.x; C written fp16 HEAD-MAJOR: C[head][row][64].

__global__ __launch_bounds__(256) void k_gemm2(const ushort_t* __restrict__ A,
                                               const ushort_t* __restrict__ BT,
                                               const float* __restrict__ as2,
                                               const float* __restrict__ ad2,
                                               ushort_t* __restrict__ C,
                                               float* __restrict__ asrc,
                                               float* __restrict__ adst, int M) {
    __shared__ short As[64 * 40];
    __shared__ short Bs[64 * 40];
    __shared__ float2 red[64][2];
    int tid = threadIdx.x;
    int row0 = blockIdx.y * 64, col0 = blockIdx.x * 64;
    int wid = tid >> 6, lane = tid & 63;
    int wm = wid >> 1, wn = wid & 1;
    int quad = lane >> 4, lm = lane & 15;
    int lr = tid >> 2, lk = (tid & 3) * 8;
    f32x4 acc[2][2] = {};
    for (int k0 = 0; k0 < FDIM; k0 += 32) {
        uint4 av = {0u, 0u, 0u, 0u};
        int ar = row0 + lr;
        if (ar < M) av = *(const uint4*)(A + (long)ar * FDIM + k0 + lk);
        *(uint4*)(&As[lr * 40 + lk]) = av;
        uint4 bv = *(const uint4*)(BT + (long)(col0 + lr) * FDIM + k0 + lk);
        *(uint4*)(&Bs[lr * 40 + lk]) = bv;
        __syncthreads();
        bf16x8 a0 = *(const bf16x8*)(&As[(wm * 32 + lm) * 40 + quad * 8]);
        bf16x8 a1 = *(const bf16x8*)(&As[(wm * 32 + 16 + lm) * 40 + quad * 8]);
        bf16x8 b0 = *(const bf16x8*)(&Bs[(wn * 32 + lm) * 40 + quad * 8]);
        bf16x8 b1 = *(const bf16x8*)(&Bs[(wn * 32 + 16 + lm) * 40 + quad * 8]);
        acc[0][0] = __builtin_amdgcn_mfma_f32_16x16x32_bf16(a0, b0, acc[0][0], 0, 0, 0);
        acc[0][1] = __builtin_amdgcn_mfma_f32_16x16x32_bf16(a0, b1, acc[0][1], 0, 0, 0);
        acc[1][0] = __builtin_amdgcn_mfma_f32_16x16x32_bf16(a1, b0, acc[1][0], 0, 0, 0);
        acc[1][1] = __builtin_amdgcn_mfma_f32_16x16x32_bf16(a1, b1, acc[1][1], 0, 0, 0);
        __syncthreads();
    }
    // C store (fp16, head-major slice = blockIdx.x)
#pragma unroll
    for (int mi = 0; mi < 2; ++mi)
#pragma unroll
        for (int ni = 0; ni < 2; ++ni)
#pragma unroll
            for (int r = 0; r < 4; ++r) {
                int row = row0 + wm * 32 + mi * 16 + quad * 4 + r;
                int colw = wn * 32 + ni * 16 + lm;
                if (row < M)
                    C[(((long)blockIdx.x * M + row) << 6) + colw] = (ushort_t)f2h(acc[mi][ni][r]);
            }
    // fused alpha2: per-row dots vs as2/ad2 (this block's head = blockIdx.x)
    float asv0 = as2[col0 + wn * 32 + lm], asv1 = as2[col0 + wn * 32 + 16 + lm];
    float adv0 = ad2[col0 + wn * 32 + lm], adv1 = ad2[col0 + wn * 32 + 16 + lm];
#pragma unroll
    for (int mi = 0; mi < 2; ++mi)
#pragma unroll
        for (int r = 0; r < 4; ++r) {
            float ps = acc[mi][0][r] * asv0 + acc[mi][1][r] * asv1;
            float pd = acc[mi][0][r] * adv0 + acc[mi][1][r] * adv1;
#pragma unroll
            for (int off = 1; off < 16; off <<= 1) {
                ps += __shfl_xor(ps, off);
                pd += __shfl_xor(pd, off);
            }
            if (lm == 0) red[wm * 32 + mi * 16 + quad * 4 + r][wn] = make_float2(ps, pd);
        }
    __syncthreads();
    if (tid < 64) {
        int row = row0 + tid;
        if (row < M) {
            float2 e0 = red[tid][0], e1 = red[tid][1];
            asrc[row * 4 + blockIdx.x] = e0.x + e1.x;
            adst[row * 4 + blockIdx.x] = e0.y + e1.y;
        }
    }
}

// ---------------- edge-parallel pw precompute: u32 = (src<<16) | fp16(pw) ----------------

__global__ void k_pw(const int2* __restrict__ csr2, const float* __restrict__ asrc,
                     const float* __restrict__ adst, uint_t* __restrict__ pwb, int Etot) {
    int e = blockIdx.x * blockDim.x + threadIdx.x;
    if (e >= Etot) return;
    int2 sd = csr2[e];
    float4 av = *(const float4*)(asrc + sd.x * 4);
    float4 dv = *(const float4*)(adst + sd.y * 4);
    float t[4] = {av.x + dv.x, av.y + dv.y, av.z + dv.z, av.w + dv.w};
    uint_t sh = (uint_t)sd.x << 16;
#pragma unroll
    for (int h = 0; h < 4; ++h) {
        float tt = (t[h] > 0.f) ? t[h] : NEG_SLOPE * t[h];
        pwb[h * Etot + e] = sh | f2h(__expf(tt));
    }
}

// ---------------- segment-softmax aggregate: ONE head per block, 8 nodes ----------------
// head = blockIdx.x & 3 -> with round-robin block->XCD dispatch, XCD k only gathers
// from head (k&3)'s 6.4 MB slice (fits mostly in 4 MB L2). pwb read non-temporally.
// mode 1: +b1, ELU, bf16 -> hout[node][256]  (MFMA A operand layout)
// mode 0: z = acc/den as fp16 -> zn[head][node][64]  (consumed by k_fin)

__global__ __launch_bounds__(256) void k_agg(const ushort_t* __restrict__ h,
                                             const uint_t* __restrict__ pwb,
                                             const int* __restrict__ row_start,
                                             const float* __restrict__ b1,
                                             ushort_t* __restrict__ hout,
                                             ushort_t* __restrict__ zn,
                                             int mode, int Etot, int N) {
    int tid  = threadIdx.x;
    int bid  = blockIdx.x;
    int head = bid & 3;
    int nb   = bid >> 2;
    int wv   = tid >> 6;
    int lane = tid & 63;
    int half = lane >> 5;
    int l32  = lane & 31;
    int g    = l32 >> 3;       // edge subgroup 0..3
    int cg   = l32 & 7;        // channel oct 0..7
    int d    = nb * 8 + wv * 2 + half;
    bool valid = d < N;

    int s0 = 0, s1 = 0;
    if (valid) { s0 = row_start[d]; s1 = row_start[d + 1]; }
    int cnt  = s1 - s0;
    int maxc = max(cnt, __shfl_xor(cnt, 32));

    const char* hb  = (const char*)h + ((size_t)head * (size_t)N << 7);  // head slice
    const char* pwc = (const char*)pwb;
    uint_t loff  = (uint_t)cg * 16;                                       // byte off in 128B row
    uint_t pbyte = ((uint_t)head * (uint_t)Etot + (uint_t)(s0 + g)) << 2; // pwb byte base

    float acc[8] = {0.f, 0.f, 0.f, 0.f, 0.f, 0.f, 0.f, 0.f};
    float den = 0.f;

    for (int off = 0; off < maxc; off += 16) {
        int i0 = s0 + off + g;
        uint_t pb = pbyte + ((uint_t)off << 2);
        uint_t u0 = (i0      < s1) ? __builtin_nontemporal_load((const uint_t*)(pwc + pb))      : 0u;
        uint_t u1 = (i0 + 4  < s1) ? __builtin_nontemporal_load((const uint_t*)(pwc + pb + 16)) : 0u;
        uint_t u2 = (i0 + 8  < s1) ? __builtin_nontemporal_load((const uint_t*)(pwc + pb + 32)) : 0u;
        uint_t u3 = (i0 + 12 < s1) ? __builtin_nontemporal_load((const uint_t*)(pwc + pb + 48)) : 0u;
        uint4 hv0 = *(const uint4*)(hb + (((u0 >> 16) << 7) + loff));
        uint4 hv1 = *(const uint4*)(hb + (((u1 >> 16) << 7) + loff));
        uint4 hv2 = *(const uint4*)(hb + (((u2 >> 16) << 7) + loff));
        uint4 hv3 = *(const uint4*)(hb + (((u3 >> 16) << 7) + loff));
        float pw0 = h2f(u0), pw1 = h2f(u1);
        float pw2 = h2f(u2), pw3 = h2f(u3);
        den += (pw0 + pw1) + (pw2 + pw3);
        fmamix8(acc, hv0, pw0);
        fmamix8(acc, hv1, pw1);
        fmamix8(acc, hv2, pw2);
        fmamix8(acc, hv3, pw3);
    }
    // reduce across the 4 edge-subgroups within each 32-lane half
#pragma unroll
    for (int off = 8; off <= 16; off <<= 1) {
#pragma unroll
        for (int j = 0; j < 8; ++j) acc[j] += __shfl_xor(acc[j], off);
        den += __shfl_xor(den, off);
    }

    if (g != 0 || !valid) return;
    float inv = 1.f / den;
    if (mode) {
        const float* bp = b1 + head * HID + cg * 8;
        float v[8];
#pragma unroll
        for (int j = 0; j < 8; ++j) {
            float t = acc[j] * inv + bp[j];
            v[j] = (t > 0.f) ? t : __expf(t) - 1.f;
        }
        u32x4 u;
        u.x = (uint_t)f2bf(v[0]) | ((uint_t)f2bf(v[1]) << 16);
        u.y = (uint_t)f2bf(v[2]) | ((uint_t)f2bf(v[3]) << 16);
        u.z = (uint_t)f2bf(v[4]) | ((uint_t)f2bf(v[5]) << 16);
        u.w = (uint_t)f2bf(v[6]) | ((uint_t)f2bf(v[7]) << 16);
        __builtin_nontemporal_store(u, (u32x4*)(hout + (long)d * FDIM + head * HID + cg * 8));
    } else {
        u32x4 u;
        u.x = f2h(acc[0] * inv) | (f2h(acc[1] * inv) << 16);
        u.y = f2h(acc[2] * inv) | (f2h(acc[3] * inv) << 16);
        u.z = f2h(acc[4] * inv) | (f2h(acc[5] * inv) << 16);
        u.w = f2h(acc[6] * inv) | (f2h(acc[7] * inv) << 16);
        __builtin_nontemporal_store(u, (u32x4*)(zn + (((long)head * N + d) << 6) + cg * 8));
    }
}

// ---------------- final epilogue: head-mean + b2 + ELU + GEMV[64x8] + bc ----------------

__global__ __launch_bounds__(256) void k_fin(const ushort_t* __restrict__ zn,
                                             const float* __restrict__ b2,
                                             const float* __restrict__ Wc,
                                             const float* __restrict__ bc,
                                             float* __restrict__ out, int N) {
    __shared__ float zsh[256];         // 4 nodes x 64 ch
    __shared__ float wsh[584];         // Wc(512) | bc(8) | b2(64)
    int tid = threadIdx.x;
    for (int i = tid; i < 584; i += 256)
        wsh[i] = (i < 512) ? Wc[i] : ((i < 520) ? bc[i - 512] : b2[i - 520]);
    __syncthreads();
    int ln = tid >> 6, c = tid & 63;
    int n = blockIdx.x * 4 + ln;
    if (n < N) {
        long base = ((long)n << 6) + c;
        long hs = (long)N << 6;
        float v = 0.25f * (h2f(zn[base]) + h2f(zn[base + hs])
                         + h2f(zn[base + 2 * hs]) + h2f(zn[base + 3 * hs]))
                + wsh[520 + c];
        zsh[ln * 64 + c] = (v > 0.f) ? v : __expf(v) - 1.f;
    }
    __syncthreads();
    if (tid < 32) {
        int ln2 = tid >> 3, o = tid & 7;
        int nn = blockIdx.x * 4 + ln2;
        if (nn < N) {
            float acc = wsh[512 + o];
            const float* zp = zsh + ln2 * 64;
#pragma unroll 8
            for (int c2 = 0; c2 < 64; ++c2) acc += zp[c2] * wsh[c2 * 8 + o];
            out[(long)nn * 8 + o] = acc;
        }
    }
}

// ---------------- launch ----------------

extern "C" void kernel_launch(void* const* d_in, const int* in_sizes, int n_in,
                              void* d_out, int out_size, void* d_ws, size_t ws_size,
                              hipStream_t stream) {
    const float* x   = (const float*)d_in[0];
    const int*   ei  = (const int*)d_in[1];
    const float* W1  = (const float*)d_in[2];
    const float* as1 = (const float*)d_in[3];
    const float* ad1 = (const float*)d_in[4];
    const float* b1  = (const float*)d_in[5];
    const float* W2  = (const float*)d_in[6];
    const float* as2 = (const float*)d_in[7];
    const float* ad2 = (const float*)d_in[8];
    const float* b2  = (const float*)d_in[9];
    const float* Wc  = (const float*)d_in[10];
    const float* bc  = (const float*)d_in[11];
    float* out = (float*)d_out;

    const int N = NODES;
    const int E = in_sizes[1] / 2;
    const int Etot = E + N;

    char* ws = (char*)d_ws;
    size_t off = 0;
    auto alloc = [&](size_t bytes) {
        void* p = ws + off;
        off = (off + bytes + 255) & ~(size_t)255;
        return p;
    };
    ushort_t* hbf    = (ushort_t*)alloc((size_t)N * FDIM * 2);   // h fp16 head-major, both layers
    ushort_t* hact   = (ushort_t*)alloc((size_t)N * FDIM * 2);   // act1 bf16 [node][256] (MFMA A)
    float*    asrc   = (float*)alloc((size_t)N * HEADS * 4);
    float*    adst   = (float*)alloc((size_t)N * HEADS * 4);
    ushort_t* W2T    = (ushort_t*)alloc((size_t)FDIM * FDIM * 2);
    int*      deg    = (int*)alloc((size_t)N * 4);
    int*      rowst  = (int*)alloc((size_t)(N + 1) * 4);
    int*      cursor = (int*)alloc((size_t)N * 4);
    int*      bsum   = (int*)alloc(64 * 4);
    int2*     csr2   = (int2*)alloc((size_t)Etot * 8);
    uint_t*   pwb    = (uint_t*)alloc((size_t)Etot * HEADS * 4);
    // znorm (fp16 [head][node][64], 25.6 MB) aliases hact: hact is dead once
    // k_gemm2 has consumed it, before the mode-0 k_agg writes znorm.
    ushort_t* znorm  = hact;

    const int tpb = 256;
    int egrid = (Etot + tpb - 1) / tpb;
    int nb = (N + 4095) / 4096;
    int NB = (N + 7) / 8;
    int agrid = 4 * ((N + 7) / 8);         // one head per block, 8 nodes

    hipMemsetAsync(deg, 0, (size_t)N * 4, stream);

    // Merged: layer-1 gemm+alpha | W2T | histogram
    k_prep<<<NB + 256 + egrid, tpb, 0, stream>>>(x, W1, as1, ad1, W2, ei, E,
                                                 hbf, asrc, adst, W2T, deg, N, NB);
    k_scanA<<<nb, 256, 0, stream>>>(deg, bsum, N);
    k_scanB<<<1, 64, 0, stream>>>(bsum, rowst, nb, N);
    k_scanC<<<nb, 256, 0, stream>>>(deg, bsum, rowst, cursor, N);
    k_scatter<<<egrid, tpb, 0, stream>>>(ei, E, N, cursor, csr2);

    // Layer 1 aggregate (+b1, ELU) -> hact
    k_pw<<<egrid, tpb, 0, stream>>>(csr2, asrc, adst, pwb, Etot);
    k_agg<<<agrid, 256, 0, stream>>>(hbf, pwb, rowst, b1, hact, nullptr, 1, Etot, N);

    // Layer 2 (gemm + fused alpha2) -> hbf (head-major fp16)
    dim3 g2(FDIM / 64, (N + 63) / 64);
    k_gemm2<<<g2, 256, 0, stream>>>(hact, W2T, as2, ad2, hbf, asrc, adst, N);
    k_pw<<<egrid, tpb, 0, stream>>>(csr2, asrc, adst, pwb, Etot);
    k_agg<<<agrid, 256, 0, stream>>>(hbf, pwb, rowst, nullptr, nullptr, znorm, 0, Etot, N);
    k_fin<<<(N + 3) / 4, 256, 0, stream>>>(znorm, b2, Wc, bc, out, N);
}